// Round 1
// baseline (1284.529 us; speedup 1.0000x reference)
//
#include <hip/hip_runtime.h>
#include <hip/hip_bf16.h>

// ---------------------------------------------------------------------------
// RNNCell encoder: seq=512, batch=512, H=IN=300.
//   prep:   W_ih, W_hh -> bf16 zero-padded [320][320]; bias = b_ih+b_hh.
//   xproj:  xp[m][n] = in[m][:]*W_ih[n][:] + bias[n]  (bf16 out, stride 300)
//   recur:  32 WGs x 256 thr (4 waves, 1 wave/SIMD). D[n][b] = W_hh * h^T.
//           R6: 5 tiles/wave (tiles w,w+4,..,w+16) = 50 W-frags = 200 AGPR.
//           At 256 thr the unified reg budget is 512/thread
//           (__launch_bounds__(256,1)) so no spill (R2-R4 spilled at 512 thr
//           where the budget was 256). Halves per-CU LDS h-panel re-reads
//           (8x10KB -> 4x10KB per step), removes t3 divergence, balances
//           waves. acc init = xp (MFMA C-in) removes one v_add per value;
//           k-loop split {a0,a1} then {a2..a4} lets tanh(0,1) hide under
//           the second MFMA block.
// ---------------------------------------------------------------------------

typedef unsigned short u16;
typedef unsigned int   u32;
typedef __attribute__((ext_vector_type(8)))  short bf16x8;
typedef __attribute__((ext_vector_type(4)))  short s16x4;
typedef __attribute__((ext_vector_type(4)))  float f32x4;
typedef __attribute__((ext_vector_type(16))) float f32x16;
typedef __attribute__((ext_vector_type(2)))  unsigned int u32x2;
typedef __attribute__((ext_vector_type(4)))  unsigned int u32x4;

#define HID 300
#define KP  320
#define SEQ 512
#define BZ  512
#define MTOT (SEQ*BZ)

__device__ __forceinline__ u16 f2bf(float f) {
    u32 u = __float_as_uint(f);
    return (u16)((u + 0x7FFFu + ((u >> 16) & 1u)) >> 16);  // RNE
}
__device__ __forceinline__ float bf2f(u16 h) {
    return __uint_as_float((u32)h << 16);
}
// tanh of an already-summed pre-activation y: 1 - 2/(exp(2y)+1)
__device__ __forceinline__ float tanh_fast(float y) {
    float e = __builtin_amdgcn_exp2f(y * 2.8853900817779268f);  // exp(2y)
    float r = __builtin_amdgcn_rcpf(e + 1.0f);
    return __builtin_fmaf(-2.0f, r, 1.0f);
}
__device__ __forceinline__ u32 pack2(float a, float b) {
    __hip_bfloat162 t = __float22bfloat162_rn(float2{a, b});  // v_cvt_pk_bf16_f32
    return *(u32*)&t;
}
// Workgroup barrier WITHOUT vmcnt drain: LDS ordering only.
__device__ __forceinline__ void lds_barrier() {
    asm volatile("s_waitcnt lgkmcnt(0)\n\ts_barrier" ::: "memory");
}

// ---------------------------------------------------------------------------
__global__ void prep_kernel(const float* __restrict__ wih,
                            const float* __restrict__ whh,
                            const float* __restrict__ bih,
                            const float* __restrict__ bhh,
                            u16* __restrict__ wihp, u16* __restrict__ whhp,
                            float* __restrict__ bias) {
    int n = blockIdx.x, k = threadIdx.x;
    bool v = (n < HID) && (k < HID);
    int src = n * HID + k, dst = n * KP + k;
    wihp[dst] = v ? f2bf(wih[src]) : (u16)0;
    whhp[dst] = v ? f2bf(whh[src]) : (u16)0;
    if (k == 0) bias[n] = (n < HID) ? (bih[n] + bhh[n]) : 0.0f;
}

// ---------------------------------------------------------------------------
// Phase 1: xp = in @ W_ih^T + bias. 2048 WGs x 512 thr. (unchanged from R4)
__global__ __launch_bounds__(512, 1) void xproj_kernel(
    const float* __restrict__ in, const u16* __restrict__ wihp,
    const float* __restrict__ bias, u16* __restrict__ xp) {
    __shared__ __align__(16) u16 As[2][4096];
    __shared__ __align__(16) u16 Bs[2][10240];

    const int tid = threadIdx.x;
    const int w = tid >> 6, l = tid & 63;
    const int mi = w & 3, ni = w >> 2;
    const int l31 = l & 31, l5 = l >> 5;
    const int m0 = blockIdx.x * 128;

    const int sm = tid >> 2, skg = tid & 3;   // A staging: row, 8-k group

    f32x16 acc[5];
#pragma unroll
    for (int j = 0; j < 5; ++j)
#pragma unroll
        for (int r = 0; r < 16; ++r) acc[j][r] = 0.0f;

    auto loadA = [&](int it, f32x4& v0, f32x4& v1) {
        int gk = it * 32 + skg * 8;
        const float* p = in + (size_t)(m0 + sm) * HID + gk;
        if (gk <= 292) { v0 = *(const f32x4*)p; v1 = *(const f32x4*)(p + 4); }
        else if (gk <= 296) { v0 = *(const f32x4*)p; v1 = f32x4{0.f,0.f,0.f,0.f}; }
        else { v0 = f32x4{0.f,0.f,0.f,0.f}; v1 = f32x4{0.f,0.f,0.f,0.f}; }
    };
    auto writeA = [&](int buf, const f32x4& v0, const f32x4& v1) {
        u32x4 pk;
        pk[0] = pack2(v0[0], v0[1]); pk[1] = pack2(v0[2], v0[3]);
        pk[2] = pack2(v1[0], v1[1]); pk[3] = pack2(v1[2], v1[3]);
        *(u32x4*)&As[buf][(skg >> 1) * 2048 + sm * 16 + (skg & 1) * 8] = pk;
    };
    auto stageB = [&](int buf, int it) {
#pragma unroll
        for (int s = 0; s < 3; ++s) {
            int i = w + 8 * s;
            if (i < 20) {
                int c = i & 3, ng = i >> 2;
                int n = ng * 64 + l;
                const u16* g = wihp + n * KP + it * 32 + c * 8;
                u16* d = &Bs[buf][c * 2560 + ng * 512];
                __builtin_amdgcn_global_load_lds(
                    (const __attribute__((address_space(1))) void*)g,
                    (__attribute__((address_space(3))) void*)d, 16, 0, 0);
            }
        }
    };

    {
        f32x4 v0, v1;
        loadA(0, v0, v1);
        writeA(0, v0, v1);
        stageB(0, 0);
    }
    __syncthreads();

#pragma unroll 1
    for (int it = 0; it < 10; ++it) {
        const int cb = it & 1, nb = (it + 1) & 1;
        f32x4 v0, v1;
        if (it < 9) {
            loadA(it + 1, v0, v1);
            stageB(nb, it + 1);
        }
#pragma unroll
        for (int s = 0; s < 2; ++s) {
            bf16x8 a = *(const bf16x8*)&As[cb][s * 2048 + mi * 512 + l31 * 16 + l5 * 8];
#pragma unroll
            for (int j = 0; j < 5; ++j) {
                bf16x8 b = *(const bf16x8*)&Bs[cb][(s * 2 + l5) * 2560 + ((ni * 5 + j) * 32 + l31) * 8];
                acc[j] = __builtin_amdgcn_mfma_f32_32x32x16_bf16(a, b, acc[j], 0, 0, 0);
            }
        }
        if (it < 9) writeA(nb, v0, v1);
        __syncthreads();
    }

    const int mbase = m0 + mi * 32;
#pragma unroll
    for (int j = 0; j < 5; ++j) {
        int n = (ni * 5 + j) * 32 + l31;
        if (n < HID) {
            float bs = bias[n];
#pragma unroll
            for (int reg = 0; reg < 16; ++reg) {
                int row = (reg & 3) + 8 * (reg >> 2) + 4 * l5;
                xp[(size_t)(mbase + row) * HID + n] = f2bf(acc[j][reg] + bs);
            }
        }
    }
}

// ---------------------------------------------------------------------------
// Phase 2: recurrence. 32 WGs x 256 thr (4 waves, 1/SIMD). Wave w owns N-tiles
// {w, w+4, w+8, w+12, w+16}. D[n][b]: A = W_hh (lane m=n), B = h^T,
// C col = b, rows = 4 consecutive n. 50 W-frags = 200 AGPR/thread; fits the
// 512-reg budget at 1 wave/EU. Per-CU LDS h-reads halve vs 8-wave version.
__global__ __launch_bounds__(256, 1) void rnn_recur_kernel(
    const u16* __restrict__ xp, const u16* __restrict__ whhp,
    float* __restrict__ out) {
    __shared__ __align__(16) u16 hb[2][16 * 328];   // double-buffered h

    const int tid = threadIdx.x;
    const int w = tid >> 6;            // wave 0..3
    const int l = tid & 63;
    const int br = l & 15;             // batch-rel (B col / C col)
    const int q  = l >> 4;             // quad
    const int b0 = blockIdx.x * 16;

    // zero both h buffers (incl. padding)
    for (int i = tid; i < (2 * 16 * 328) / 2; i += 256) ((u32*)hb)[i] = 0;

    // W_hh A-fragments (load once; pinned to AGPRs). 5 tiles x 10 ks.
    bf16x8 Af[5][10];
#pragma unroll
    for (int j = 0; j < 5; ++j) {
        const int nt = w + 4 * j;
        const u16* wrow = whhp + (size_t)(nt * 16 + br) * KP;
#pragma unroll
        for (int ks = 0; ks < 10; ++ks)
            Af[j][ks] = *(const bf16x8*)(wrow + ks * 32 + q * 8);
    }
#pragma unroll
    for (int j = 0; j < 5; ++j)
#pragma unroll
        for (int ks = 0; ks < 10; ++ks)
            asm volatile("" : "+a"(Af[j][ks]));

    // xp element offsets (step-invariant); -1 = fully-padded quad
    int xo[5];
#pragma unroll
    for (int j = 0; j < 5; ++j) {
        int n0 = (w + 4 * j) * 16 + q * 4;
        xo[j] = (n0 < HID) ? ((b0 + br) * HID + n0) : -1;
    }

    const s16x4 z4 = {0, 0, 0, 0};
    s16x4 xc[5], xn[5];
#pragma unroll
    for (int j = 0; j < 5; ++j) {
        xc[j] = (xo[j] >= 0) ? *(const s16x4*)(xp + xo[j]) : z4;
        xn[j] = (xo[j] >= 0) ? *(const s16x4*)(xp + (size_t)BZ * HID + xo[j]) : z4;
    }

    lds_barrier();

#pragma unroll 1
    for (int t = 0; t < SEQ; ++t) {
        const u16* hc = hb[t & 1];
        u16*       hn = hb[(t + 1) & 1];

        // prefetch xp for t+2 (raw barrier keeps vmcnt free -> stays in flight)
        s16x4 xf[5];
        {
            int t2 = (t + 2 < SEQ) ? (t + 2) : (SEQ - 1);
            const u16* base = xp + (size_t)t2 * (BZ * HID);
#pragma unroll
            for (int j = 0; j < 5; ++j)
                xf[j] = (xo[j] >= 0) ? *(const s16x4*)(base + xo[j]) : z4;
        }

        // acc init = xp contribution (MFMA C-in); pad quads init to 0.
        f32x4 a[5];
#pragma unroll
        for (int j = 0; j < 5; ++j)
#pragma unroll
            for (int r = 0; r < 4; ++r)
                a[j][r] = bf2f((u16)xc[j][r]);

        // k-loop part 1: chains a0,a1; keep all B-frags in regs for part 2.
        bf16x8 bfr[10];
#pragma unroll
        for (int ks = 0; ks < 10; ++ks) {
            bfr[ks] = *(const bf16x8*)&hc[br * 328 + ks * 32 + q * 8];
            a[0] = __builtin_amdgcn_mfma_f32_16x16x32_bf16(Af[0][ks], bfr[ks], a[0], 0, 0, 0);
            a[1] = __builtin_amdgcn_mfma_f32_16x16x32_bf16(Af[1][ks], bfr[ks], a[1], 0, 0, 0);
        }

        // tanh+write tiles 0,1 -- sourced before part 2 so the scheduler can
        // sink this VALU under the a2..a4 MFMA block (separate pipes).
#pragma unroll
        for (int j = 0; j < 2; ++j) {
            int n0 = (w + 4 * j) * 16 + q * 4;
            u32x2 pk;
            pk[0] = pack2(tanh_fast(a[j][0]), tanh_fast(a[j][1]));
            pk[1] = pack2(tanh_fast(a[j][2]), tanh_fast(a[j][3]));
            *(u32x2*)&hn[br * 328 + n0] = pk;
        }

        // k-loop part 2: chains a2..a4 from register-resident B-frags.
#pragma unroll
        for (int ks = 0; ks < 10; ++ks) {
            a[2] = __builtin_amdgcn_mfma_f32_16x16x32_bf16(Af[2][ks], bfr[ks], a[2], 0, 0, 0);
            a[3] = __builtin_amdgcn_mfma_f32_16x16x32_bf16(Af[3][ks], bfr[ks], a[3], 0, 0, 0);
            a[4] = __builtin_amdgcn_mfma_f32_16x16x32_bf16(Af[4][ks], bfr[ks], a[4], 0, 0, 0);
        }

#pragma unroll
        for (int j = 2; j < 5; ++j) {
            int n0 = (w + 4 * j) * 16 + q * 4;
            u32x2 pk;
            pk[0] = pack2(tanh_fast(a[j][0]), tanh_fast(a[j][1]));
            pk[1] = pack2(tanh_fast(a[j][2]), tanh_fast(a[j][3]));
            *(u32x2*)&hn[br * 328 + n0] = pk;
        }

        lds_barrier();   // LDS-only ordering; xp loads stay in flight

#pragma unroll
        for (int j = 0; j < 5; ++j) { xc[j] = xn[j]; xn[j] = xf[j]; }
    }

    // final h_512 lives in hb[0] (512 even)
    const u16* hf = hb[0];
    for (int i = tid; i < 16 * HID; i += 256) {
        int r = i / HID, n = i - r * HID;
        out[(size_t)(b0 + r) * HID + n] = bf2f(hf[r * 328 + n]);
    }
}

// ---------------------------------------------------------------------------
extern "C" void kernel_launch(void* const* d_in, const int* in_sizes, int n_in,
                              void* d_out, int out_size, void* d_ws, size_t ws_size,
                              hipStream_t stream) {
    const float* in  = (const float*)d_in[0];
    const float* wih = (const float*)d_in[1];
    const float* whh = (const float*)d_in[2];
    const float* bih = (const float*)d_in[3];
    const float* bhh = (const float*)d_in[4];

    char* ws = (char*)d_ws;
    const size_t XP_BYTES = (size_t)MTOT * HID * sizeof(u16);   // 157,286,400
    u16*   xpb  = (u16*)ws;
    u16*   wihp = (u16*)(ws + XP_BYTES);
    u16*   whhp = (u16*)(ws + XP_BYTES + (size_t)KP * KP * 2);
    float* bias = (float*)(ws + XP_BYTES + 2 * (size_t)KP * KP * 2);

    prep_kernel<<<KP, KP, 0, stream>>>(wih, whh, bih, bhh, wihp, whhp, bias);
    xproj_kernel<<<MTOT / 128, 512, 0, stream>>>(in, wihp, bias, xpb);
    rnn_recur_kernel<<<BZ / 16, 256, 0, stream>>>(xpb, whhp, (float*)d_out);
}

// Round 2
// 1204.256 us; speedup vs baseline: 1.0667x; 1.0667x over previous
//
#include <hip/hip_runtime.h>
#include <hip/hip_bf16.h>

// ---------------------------------------------------------------------------
// RNNCell encoder: seq=512, batch=512, H=IN=300.
//   prep:   W_ih, W_hh -> bf16 zero-padded [320][320]; bias = b_ih+b_hh.
//   xproj:  R7 REWRITE: no LDS, no barriers. 2048 WGs x 256 thr (4 waves).
//           Wave (mi,ni) owns rows m0+mi*64..+63 (2 blocks of 32) x n-tiles
//           ni*5..ni*5+4 (32 wide). A-frags straight from global f32 + cvt_pk;
//           B-frags (wihp, L2-hot) straight from global as b128. acc = 160
//           VGPR; __launch_bounds__(256,2) caps regs at 256 so 2 WGs/CU
//           co-reside -> 2 waves/SIMD of independent WGs hide latency.
//           Old version drained vmcnt(0) at a barrier every k-iter (~900cy
//           HBM latency exposed x10) -> was ~525us vs 75us HBM floor.
//   recur:  R5 verbatim (562us known-good). R6's 4-wave/1-per-SIMD variant
//           regressed to 758us: latency-bound, no partner wave to hide LDS
//           read latency / MFMA dep chains / serial tanh. Keep 2 waves/SIMD.
// ---------------------------------------------------------------------------

typedef unsigned short u16;
typedef unsigned int   u32;
typedef __attribute__((ext_vector_type(8)))  short bf16x8;
typedef __attribute__((ext_vector_type(4)))  short s16x4;
typedef __attribute__((ext_vector_type(4)))  float f32x4;
typedef __attribute__((ext_vector_type(16))) float f32x16;
typedef __attribute__((ext_vector_type(2)))  unsigned int u32x2;
typedef __attribute__((ext_vector_type(4)))  unsigned int u32x4;

#define HID 300
#define KP  320
#define SEQ 512
#define BZ  512
#define MTOT (SEQ*BZ)

__device__ __forceinline__ u16 f2bf(float f) {
    u32 u = __float_as_uint(f);
    return (u16)((u + 0x7FFFu + ((u >> 16) & 1u)) >> 16);  // RNE
}
__device__ __forceinline__ float bf2f(u16 h) {
    return __uint_as_float((u32)h << 16);
}
__device__ __forceinline__ float tanh_fast(float x) {
    float e = __builtin_amdgcn_exp2f(x * 2.8853900817779268f);  // exp(2x)
    float r = __builtin_amdgcn_rcpf(e + 1.0f);
    return __builtin_fmaf(-2.0f, r, 1.0f);
}
__device__ __forceinline__ u32 pack2(float a, float b) {
    __hip_bfloat162 t = __float22bfloat162_rn(float2{a, b});  // v_cvt_pk_bf16_f32
    return *(u32*)&t;
}
// Workgroup barrier WITHOUT vmcnt drain: LDS ordering only.
__device__ __forceinline__ void lds_barrier() {
    asm volatile("s_waitcnt lgkmcnt(0)\n\ts_barrier" ::: "memory");
}

// ---------------------------------------------------------------------------
__global__ void prep_kernel(const float* __restrict__ wih,
                            const float* __restrict__ whh,
                            const float* __restrict__ bih,
                            const float* __restrict__ bhh,
                            u16* __restrict__ wihp, u16* __restrict__ whhp,
                            float* __restrict__ bias) {
    int n = blockIdx.x, k = threadIdx.x;
    bool v = (n < HID) && (k < HID);
    int src = n * HID + k, dst = n * KP + k;
    wihp[dst] = v ? f2bf(wih[src]) : (u16)0;
    whhp[dst] = v ? f2bf(whh[src]) : (u16)0;
    if (k == 0) bias[n] = (n < HID) ? (bih[n] + bhh[n]) : 0.0f;
}

// ---------------------------------------------------------------------------
// Phase 1 (R7): xp = in @ W_ih^T + bias. 2048 WGs x 256 thr, LDS-free,
// barrier-free. 19 k-iters of 16 (k 0..303; A masked at k>=300, wihp rows
// n>=300 and cols k>=300 are zero). Manual register double-buffer of frags.
__global__ __launch_bounds__(256, 2) void xproj_kernel(
    const float* __restrict__ in, const u16* __restrict__ wihp,
    const float* __restrict__ bias, u16* __restrict__ xp) {
    const int tid = threadIdx.x;
    const int w   = tid >> 6;          // wave 0..3
    const int l   = tid & 63;
    const int l31 = l & 31, l5 = l >> 5;
    const int mi  = w & 1, ni = w >> 1;
    const int m0  = blockIdx.x * 128 + mi * 64;   // wave's first row

    // A: lane l -> row m0 + rb*32 + l31, k-chunk l5*8 (8 consecutive k).
    const int aoff0 = (m0 + l31) * HID + l5 * 8;
    const int aoff1 = aoff0 + 32 * HID;
    // B: lane l -> col n = (ni*5+j)*32 + l31, k-chunk l5*8.
    int boff[5];
#pragma unroll
    for (int j = 0; j < 5; ++j)
        boff[j] = ((ni * 5 + j) * 32 + l31) * KP + l5 * 8;

    f32x16 acc0[5], acc1[5];
#pragma unroll
    for (int j = 0; j < 5; ++j)
#pragma unroll
        for (int r = 0; r < 16; ++r) { acc0[j][r] = 0.0f; acc1[j][r] = 0.0f; }

    auto mkfrag = [](const f32x4& u0, const f32x4& u1) -> bf16x8 {
        union { u32x4 u; bf16x8 b; } cv;
        cv.u[0] = pack2(u0[0], u0[1]); cv.u[1] = pack2(u0[2], u0[3]);
        cv.u[2] = pack2(u1[0], u1[1]); cv.u[3] = pack2(u1[2], u1[3]);
        return cv.b;
    };
    const f32x4 zf = {0.f, 0.f, 0.f, 0.f};

    auto loadA = [&](int it, bf16x8& A0, bf16x8& A1, bool last) {
        const float* p0 = in + aoff0 + it * 16;
        const float* p1 = in + aoff1 + it * 16;
        f32x4 u0 = *(const f32x4*)p0;
        f32x4 w0 = *(const f32x4*)p1;
        f32x4 u1, w1;
        if (last && l5 == 1) { u1 = zf; w1 = zf; }   // k 300..303 -> 0
        else { u1 = *(const f32x4*)(p0 + 4); w1 = *(const f32x4*)(p1 + 4); }
        A0 = mkfrag(u0, u1);
        A1 = mkfrag(w0, w1);
    };
    auto loadB = [&](int it, bf16x8* B) {
#pragma unroll
        for (int j = 0; j < 5; ++j)
            B[j] = *(const bf16x8*)(wihp + boff[j] + it * 16);
    };

    bf16x8 A0c, A1c, Bc[5];
    loadA(0, A0c, A1c, false);
    loadB(0, Bc);

#pragma unroll 1
    for (int it = 0; it < 18; ++it) {
        bf16x8 A0n, A1n, Bn[5];
        loadA(it + 1, A0n, A1n, it + 1 == 18);
        loadB(it + 1, Bn);
#pragma unroll
        for (int j = 0; j < 5; ++j) {
            acc0[j] = __builtin_amdgcn_mfma_f32_32x32x16_bf16(A0c, Bc[j], acc0[j], 0, 0, 0);
            acc1[j] = __builtin_amdgcn_mfma_f32_32x32x16_bf16(A1c, Bc[j], acc1[j], 0, 0, 0);
        }
        A0c = A0n; A1c = A1n;
#pragma unroll
        for (int j = 0; j < 5; ++j) Bc[j] = Bn[j];
    }
#pragma unroll
    for (int j = 0; j < 5; ++j) {
        acc0[j] = __builtin_amdgcn_mfma_f32_32x32x16_bf16(A0c, Bc[j], acc0[j], 0, 0, 0);
        acc1[j] = __builtin_amdgcn_mfma_f32_32x32x16_bf16(A1c, Bc[j], acc1[j], 0, 0, 0);
    }

    // Epilogue: C layout col=l31, row=(reg&3)+8*(reg>>2)+4*l5 (proven m74/m101).
#pragma unroll
    for (int j = 0; j < 5; ++j) {
        int n = (ni * 5 + j) * 32 + l31;
        if (n < HID) {
            float bs = bias[n];
            int rbase = m0 + 4 * l5;
#pragma unroll
            for (int reg = 0; reg < 16; ++reg) {
                int row = rbase + (reg & 3) + 8 * (reg >> 2);
                xp[(size_t)row * HID + n] = f2bf(acc0[j][reg] + bs);
                xp[(size_t)(row + 32) * HID + n] = f2bf(acc1[j][reg] + bs);
            }
        }
    }
}

// ---------------------------------------------------------------------------
// Phase 2: recurrence. 32 WGs x 512 thr (8 waves). Wave w owns N-tiles
// {w, w+8, w+16<only w<4>} of 20. D[n][b]: A = W_hh (lane m=n), B = h^T,
// C col = b, rows = 4 consecutive n. Max 30 W-frags = 120 AGPR/thread.
// (R5 verbatim -- 562us known-good; R6's 1-wave/SIMD variant regressed.)
__global__ __launch_bounds__(512, 2) void rnn_recur_kernel(
    const u16* __restrict__ xp, const u16* __restrict__ whhp,
    float* __restrict__ out) {
    __shared__ __align__(16) u16 hb[2][16 * 328];   // double-buffered h

    const int tid = threadIdx.x;
    const int w = tid >> 6;            // wave 0..7
    const int l = tid & 63;
    const int br = l & 15;             // batch-rel (B col / C col)
    const int q  = l >> 4;             // quad
    const int b0 = blockIdx.x * 16;
    const bool t3 = (w < 4);           // waves 0-3 own a third tile

    // zero both h buffers (incl. padding)
    for (int i = tid; i < (2 * 16 * 328) / 2; i += 512) ((u32*)hb)[i] = 0;

    // W_hh A-fragments (load once; pinned to AGPRs)
    bf16x8 Af[3][10];
#pragma unroll
    for (int j = 0; j < 3; ++j) {
        if (j < 2 || t3) {
            const int nt = w + 8 * j;
            const u16* wrow = whhp + (size_t)(nt * 16 + br) * KP;
#pragma unroll
            for (int ks = 0; ks < 10; ++ks)
                Af[j][ks] = *(const bf16x8*)(wrow + ks * 32 + q * 8);
        }
    }
#pragma unroll
    for (int j = 0; j < 3; ++j)
        if (j < 2 || t3)
#pragma unroll
            for (int ks = 0; ks < 10; ++ks)
                asm volatile("" : "+a"(Af[j][ks]));

    // xp element offsets (step-invariant); -1 = fully-padded quad
    int xo[3];
#pragma unroll
    for (int j = 0; j < 3; ++j) {
        int n0 = (w + 8 * j) * 16 + q * 4;
        xo[j] = (n0 < HID && (j < 2 || t3)) ? ((b0 + br) * HID + n0) : -1;
    }

    const s16x4 z4 = {0, 0, 0, 0};
    s16x4 xc[3], xn[3];
#pragma unroll
    for (int j = 0; j < 3; ++j) {
        xc[j] = (xo[j] >= 0) ? *(const s16x4*)(xp + xo[j]) : z4;
        xn[j] = (xo[j] >= 0) ? *(const s16x4*)(xp + (size_t)BZ * HID + xo[j]) : z4;
    }

    lds_barrier();

#pragma unroll 1
    for (int t = 0; t < SEQ; ++t) {
        const u16* hc = hb[t & 1];
        u16*       hn = hb[(t + 1) & 1];

        // prefetch xp for t+2 (raw barrier keeps vmcnt free -> stays in flight)
        s16x4 xf[3];
        {
            int t2 = (t + 2 < SEQ) ? (t + 2) : (SEQ - 1);
            const u16* base = xp + (size_t)t2 * (BZ * HID);
#pragma unroll
            for (int j = 0; j < 3; ++j)
                xf[j] = (xo[j] >= 0) ? *(const s16x4*)(base + xo[j]) : z4;
        }

        f32x4 a0, a1, a2;
#pragma unroll
        for (int r = 0; r < 4; ++r) { a0[r] = 0.f; a1[r] = 0.f; a2[r] = 0.f; }

#pragma unroll
        for (int ks = 0; ks < 10; ++ks) {
            bf16x8 bfr = *(const bf16x8*)&hc[br * 328 + ks * 32 + q * 8];
            a0 = __builtin_amdgcn_mfma_f32_16x16x32_bf16(Af[0][ks], bfr, a0, 0, 0, 0);
            a1 = __builtin_amdgcn_mfma_f32_16x16x32_bf16(Af[1][ks], bfr, a1, 0, 0, 0);
            if (t3)
                a2 = __builtin_amdgcn_mfma_f32_16x16x32_bf16(Af[2][ks], bfr, a2, 0, 0, 0);
        }

        // h[b][n0..n0+3] = tanh(acc + xp); pad cols: acc=0, xc=0 -> tanh(0)=0
        {
            int n0 = w * 16 + q * 4;
            u32x2 pk;
            pk[0] = pack2(tanh_fast(a0[0] + bf2f((u16)xc[0][0])),
                          tanh_fast(a0[1] + bf2f((u16)xc[0][1])));
            pk[1] = pack2(tanh_fast(a0[2] + bf2f((u16)xc[0][2])),
                          tanh_fast(a0[3] + bf2f((u16)xc[0][3])));
            *(u32x2*)&hn[br * 328 + n0] = pk;
        }
        {
            int n0 = (w + 8) * 16 + q * 4;
            u32x2 pk;
            pk[0] = pack2(tanh_fast(a1[0] + bf2f((u16)xc[1][0])),
                          tanh_fast(a1[1] + bf2f((u16)xc[1][1])));
            pk[1] = pack2(tanh_fast(a1[2] + bf2f((u16)xc[1][2])),
                          tanh_fast(a1[3] + bf2f((u16)xc[1][3])));
            *(u32x2*)&hn[br * 328 + n0] = pk;
        }
        if (t3) {
            int n0 = (w + 16) * 16 + q * 4;
            u32x2 pk;
            pk[0] = pack2(tanh_fast(a2[0] + bf2f((u16)xc[2][0])),
                          tanh_fast(a2[1] + bf2f((u16)xc[2][1])));
            pk[1] = pack2(tanh_fast(a2[2] + bf2f((u16)xc[2][2])),
                          tanh_fast(a2[3] + bf2f((u16)xc[2][3])));
            *(u32x2*)&hn[br * 328 + n0] = pk;
        }
        lds_barrier();   // LDS-only ordering; xp loads stay in flight

#pragma unroll
        for (int j = 0; j < 3; ++j) { xc[j] = xn[j]; xn[j] = xf[j]; }
    }

    // final h_512 lives in hb[0] (512 even)
    const u16* hf = hb[0];
    for (int i = tid; i < 16 * HID; i += 512) {
        int r = i / HID, n = i - r * HID;
        out[(size_t)(b0 + r) * HID + n] = bf2f(hf[r * 328 + n]);
    }
}

// ---------------------------------------------------------------------------
extern "C" void kernel_launch(void* const* d_in, const int* in_sizes, int n_in,
                              void* d_out, int out_size, void* d_ws, size_t ws_size,
                              hipStream_t stream) {
    const float* in  = (const float*)d_in[0];
    const float* wih = (const float*)d_in[1];
    const float* whh = (const float*)d_in[2];
    const float* bih = (const float*)d_in[3];
    const float* bhh = (const float*)d_in[4];

    char* ws = (char*)d_ws;
    const size_t XP_BYTES = (size_t)MTOT * HID * sizeof(u16);   // 157,286,400
    u16*   xpb  = (u16*)ws;
    u16*   wihp = (u16*)(ws + XP_BYTES);
    u16*   whhp = (u16*)(ws + XP_BYTES + (size_t)KP * KP * 2);
    float* bias = (float*)(ws + XP_BYTES + 2 * (size_t)KP * KP * 2);

    prep_kernel<<<KP, KP, 0, stream>>>(wih, whh, bih, bhh, wihp, whhp, bias);
    xproj_kernel<<<MTOT / 128, 256, 0, stream>>>(in, wihp, bias, xpb);
    rnn_recur_kernel<<<BZ / 16, 512, 0, stream>>>(xpb, whhp, (float*)d_out);
}

// Round 3
// 1093.416 us; speedup vs baseline: 1.1748x; 1.1014x over previous
//
#include <hip/hip_runtime.h>
#include <hip/hip_bf16.h>

// ---------------------------------------------------------------------------
// RNNCell encoder: seq=512, batch=512, H=IN=300.
//   prep:   W_ih, W_hh -> bf16 zero-padded [320][320]; bias = b_ih+b_hh.
//   xproj:  R8: R4 LDS structure + T3/T4 counted-vmcnt pipeline.
//           Bs triple-buffered (stage 2 iters ahead), As double-buffered.
//           Per-iter sync = s_waitcnt vmcnt(3) + lgkmcnt barrier -- never a
//           full vmcnt(0) drain; global_load_lds stays in flight one full
//           compute phase. loadA made branchless (clamped addrs + reg mask)
//           so per-wave VMEM counts are uniform and the hand-counted vmcnt
//           is exact (waves 0-3 stage 3 glls, 4-7 stage 2; vmcnt(3)/(2)
//           verified for both under FIFO retirement).
//   recur:  R5 inner loop verbatim (562us known-good), split into two
//           dispatches (t 0..255, 256..511); h handed off as bf16 via d_out
//           storage (rewritten with f32 at the end). Purpose: surface xproj
//           in the rocprof top-5 (recur halves ~280us) to resolve the
//           missing-~450us attribution question. R6 lesson kept: 8 waves,
//           2/SIMD.
// ---------------------------------------------------------------------------

typedef unsigned short u16;
typedef unsigned int   u32;
typedef __attribute__((ext_vector_type(8)))  short bf16x8;
typedef __attribute__((ext_vector_type(4)))  short s16x4;
typedef __attribute__((ext_vector_type(4)))  float f32x4;
typedef __attribute__((ext_vector_type(16))) float f32x16;
typedef __attribute__((ext_vector_type(2)))  unsigned int u32x2;
typedef __attribute__((ext_vector_type(4)))  unsigned int u32x4;

#define HID 300
#define KP  320
#define SEQ 512
#define BZ  512
#define MTOT (SEQ*BZ)

__device__ __forceinline__ u16 f2bf(float f) {
    u32 u = __float_as_uint(f);
    return (u16)((u + 0x7FFFu + ((u >> 16) & 1u)) >> 16);  // RNE
}
__device__ __forceinline__ float bf2f(u16 h) {
    return __uint_as_float((u32)h << 16);
}
__device__ __forceinline__ float tanh_fast(float x) {
    float e = __builtin_amdgcn_exp2f(x * 2.8853900817779268f);  // exp(2x)
    float r = __builtin_amdgcn_rcpf(e + 1.0f);
    return __builtin_fmaf(-2.0f, r, 1.0f);
}
__device__ __forceinline__ u32 pack2(float a, float b) {
    __hip_bfloat162 t = __float22bfloat162_rn(float2{a, b});  // v_cvt_pk_bf16_f32
    return *(u32*)&t;
}
// Workgroup barrier WITHOUT vmcnt drain: LDS ordering only.
__device__ __forceinline__ void lds_barrier() {
    asm volatile("s_waitcnt lgkmcnt(0)\n\ts_barrier" ::: "memory");
}

// ---------------------------------------------------------------------------
__global__ void prep_kernel(const float* __restrict__ wih,
                            const float* __restrict__ whh,
                            const float* __restrict__ bih,
                            const float* __restrict__ bhh,
                            u16* __restrict__ wihp, u16* __restrict__ whhp,
                            float* __restrict__ bias) {
    int n = blockIdx.x, k = threadIdx.x;
    bool v = (n < HID) && (k < HID);
    int src = n * HID + k, dst = n * KP + k;
    wihp[dst] = v ? f2bf(wih[src]) : (u16)0;
    whhp[dst] = v ? f2bf(whh[src]) : (u16)0;
    if (k == 0) bias[n] = (n < HID) ? (bih[n] + bhh[n]) : 0.0f;
}

// ---------------------------------------------------------------------------
// Phase 1 (R8): xp = in @ W_ih^T + bias. 2048 WGs x 512 thr.
// LDS: As[2] (A double-buf) + Bs[3] (B triple-buf, staged 2 ahead) = 76 KB.
__global__ __launch_bounds__(512, 1) void xproj_kernel(
    const float* __restrict__ in, const u16* __restrict__ wihp,
    const float* __restrict__ bias, u16* __restrict__ xp) {
    __shared__ __align__(16) u16 As[2][4096];
    __shared__ __align__(16) u16 Bs[3][10240];

    const int tid = threadIdx.x;
    const int w = tid >> 6, l = tid & 63;
    const int mi = w & 3, ni = w >> 2;
    const int l31 = l & 31, l5 = l >> 5;
    const int m0 = blockIdx.x * 128;

    const int sm = tid >> 2, skg = tid & 3;   // A staging: row, 8-k group

    f32x16 acc[5];
#pragma unroll
    for (int j = 0; j < 5; ++j)
#pragma unroll
        for (int r = 0; r < 16; ++r) acc[j][r] = 0.0f;

    const f32x4 zf = {0.f, 0.f, 0.f, 0.f};
    // Branchless A-load: always 2 VMEM ops (uniform vmcnt), clamp addr to
    // stay in-bounds, zero invalid k in registers. gk multiples of 8; only
    // it=9 produces gk >= 296 cases.
    auto loadA = [&](int it, f32x4& v0, f32x4& v1) {
        int gk = it * 32 + skg * 8;
        int a0 = gk > 296 ? 296 : gk;
        int a1 = (gk + 4) > 296 ? 296 : (gk + 4);
        const float* p = in + (size_t)(m0 + sm) * HID;
        v0 = *(const f32x4*)(p + a0);
        v1 = *(const f32x4*)(p + a1);
        v0 = (gk > 296) ? zf : v0;        // gk>=304: fully padded
        v1 = ((gk + 4) > 296) ? zf : v1;  // k 300..303 -> 0
    };
    auto writeA = [&](int buf, const f32x4& v0, const f32x4& v1) {
        u32x4 pk;
        pk[0] = pack2(v0[0], v0[1]); pk[1] = pack2(v0[2], v0[3]);
        pk[2] = pack2(v1[0], v1[1]); pk[3] = pack2(v1[2], v1[3]);
        *(u32x4*)&As[buf][(skg >> 1) * 2048 + sm * 16 + (skg & 1) * 8] = pk;
    };
    auto stageB = [&](int buf, int it) {
#pragma unroll
        for (int s = 0; s < 3; ++s) {
            int i = w + 8 * s;                // wave-uniform predicate
            if (i < 20) {
                int c = i & 3, ng = i >> 2;
                int n = ng * 64 + l;
                const u16* g = wihp + n * KP + it * 32 + c * 8;
                u16* d = &Bs[buf][c * 2560 + ng * 512];
                __builtin_amdgcn_global_load_lds(
                    (const __attribute__((address_space(1))) void*)g,
                    (__attribute__((address_space(3))) void*)d, 16, 0, 0);
            }
        }
    };

    // Prologue: stage B for it=0 and it=1; A for it=0.
    {
        stageB(0, 0);
        f32x4 v0, v1;
        loadA(0, v0, v1);
        writeA(0, v0, v1);
        stageB(1, 1);
        // outstanding glls: buf0 (3 or 2) + buf1 (3 or 2); wait buf0 done.
        asm volatile("s_waitcnt vmcnt(2)" ::: "memory");
        lds_barrier();
    }

    int cA = 0, cB = 0, sB = 2;
#pragma unroll 1
    for (int it = 0; it < 10; ++it) {
        f32x4 v0, v1;
        if (it < 9) loadA(it + 1, v0, v1);
        if (it < 8) stageB(sB, it + 2);
#pragma unroll
        for (int s = 0; s < 2; ++s) {
            bf16x8 a = *(const bf16x8*)&As[cA][s * 2048 + mi * 512 + l31 * 16 + l5 * 8];
#pragma unroll
            for (int j = 0; j < 5; ++j) {
                bf16x8 b = *(const bf16x8*)&Bs[cB][(s * 2 + l5) * 2560 + ((ni * 5 + j) * 32 + l31) * 8];
                acc[j] = __builtin_amdgcn_mfma_f32_32x32x16_bf16(a, b, acc[j], 0, 0, 0);
            }
        }
        if (it < 9) {
            writeA(cA ^ 1, v0, v1);
            // Ensure glls for buffer (it+1) have landed before the barrier;
            // glls for (it+2) (newest 3) stay in flight. Tail iter has no
            // new stage -> tighter count.
            if (it < 8) asm volatile("s_waitcnt vmcnt(3)" ::: "memory");
            else        asm volatile("s_waitcnt vmcnt(2)" ::: "memory");
            lds_barrier();
        }
        cA ^= 1;
        cB = (cB == 2) ? 0 : cB + 1;
        sB = (sB == 2) ? 0 : sB + 1;
    }

    const int mbase = m0 + mi * 32;
#pragma unroll
    for (int j = 0; j < 5; ++j) {
        int n = (ni * 5 + j) * 32 + l31;
        if (n < HID) {
            float bs = bias[n];
#pragma unroll
            for (int reg = 0; reg < 16; ++reg) {
                int row = (reg & 3) + 8 * (reg >> 2) + 4 * l5;
                xp[(size_t)(mbase + row) * HID + n] = f2bf(acc[j][reg] + bs);
            }
        }
    }
}

// ---------------------------------------------------------------------------
// Phase 2: recurrence over t in [t0, t1). 32 WGs x 512 thr (8 waves).
// Wave w owns N-tiles {w, w+8, w+16<only w<4>} of 20. Inner loop = R5
// verbatim. h handoff between the two dispatches: bf16 in d_out storage
// (dispatch boundary gives device-wide visibility); final dispatch
// overwrites d_out with f32 h_512.
__global__ __launch_bounds__(512, 2) void rnn_recur_kernel(
    const u16* __restrict__ xp, const u16* __restrict__ whhp,
    float* __restrict__ out, int t0, int t1) {
    __shared__ __align__(16) u16 hb[2][16 * 328];   // double-buffered h

    const int tid = threadIdx.x;
    const int w = tid >> 6;            // wave 0..7
    const int l = tid & 63;
    const int br = l & 15;             // batch-rel (B col / C col)
    const int q  = l >> 4;             // quad
    const int b0 = blockIdx.x * 16;
    const bool t3 = (w < 4);           // waves 0-3 own a third tile

    // zero both h buffers (incl. padding)
    for (int i = tid; i < (2 * 16 * 328) / 2; i += 512) ((u32*)hb)[i] = 0;

    // W_hh A-fragments (load once; pinned to AGPRs)
    bf16x8 Af[3][10];
#pragma unroll
    for (int j = 0; j < 3; ++j) {
        if (j < 2 || t3) {
            const int nt = w + 8 * j;
            const u16* wrow = whhp + (size_t)(nt * 16 + br) * KP;
#pragma unroll
            for (int ks = 0; ks < 10; ++ks)
                Af[j][ks] = *(const bf16x8*)(wrow + ks * 32 + q * 8);
        }
    }
#pragma unroll
    for (int j = 0; j < 3; ++j)
        if (j < 2 || t3)
#pragma unroll
            for (int ks = 0; ks < 10; ++ks)
                asm volatile("" : "+a"(Af[j][ks]));

    // h handoff load (t0>0): current buffer at entry is hb[t0&1]=hb[0].
    lds_barrier();   // order: zeroing vs handoff writes (different thr maps)
    if (t0 > 0) {
        const u16* hs = (const u16*)out;
        for (int i = tid; i < 16 * HID; i += 512) {
            int r = i / HID, n = i - r * HID;
            hb[0][r * 328 + n] = hs[(size_t)(b0 + r) * HID + n];
        }
    }

    // xp element offsets (step-invariant); -1 = fully-padded quad
    int xo[3];
#pragma unroll
    for (int j = 0; j < 3; ++j) {
        int n0 = (w + 8 * j) * 16 + q * 4;
        xo[j] = (n0 < HID && (j < 2 || t3)) ? ((b0 + br) * HID + n0) : -1;
    }

    const s16x4 z4 = {0, 0, 0, 0};
    s16x4 xc[3], xn[3];
#pragma unroll
    for (int j = 0; j < 3; ++j) {
        xc[j] = (xo[j] >= 0) ? *(const s16x4*)(xp + (size_t)t0 * (BZ * HID) + xo[j]) : z4;
        xn[j] = (xo[j] >= 0) ? *(const s16x4*)(xp + (size_t)(t0 + 1) * (BZ * HID) + xo[j]) : z4;
    }

    lds_barrier();

#pragma unroll 1
    for (int t = t0; t < t1; ++t) {
        const u16* hc = hb[t & 1];
        u16*       hn = hb[(t + 1) & 1];

        // prefetch xp for t+2 (raw barrier keeps vmcnt free -> stays in flight)
        s16x4 xf[3];
        {
            int t2 = (t + 2 < SEQ) ? (t + 2) : (SEQ - 1);
            const u16* base = xp + (size_t)t2 * (BZ * HID);
#pragma unroll
            for (int j = 0; j < 3; ++j)
                xf[j] = (xo[j] >= 0) ? *(const s16x4*)(base + xo[j]) : z4;
        }

        f32x4 a0, a1, a2;
#pragma unroll
        for (int r = 0; r < 4; ++r) { a0[r] = 0.f; a1[r] = 0.f; a2[r] = 0.f; }

#pragma unroll
        for (int ks = 0; ks < 10; ++ks) {
            bf16x8 bfr = *(const bf16x8*)&hc[br * 328 + ks * 32 + q * 8];
            a0 = __builtin_amdgcn_mfma_f32_16x16x32_bf16(Af[0][ks], bfr, a0, 0, 0, 0);
            a1 = __builtin_amdgcn_mfma_f32_16x16x32_bf16(Af[1][ks], bfr, a1, 0, 0, 0);
            if (t3)
                a2 = __builtin_amdgcn_mfma_f32_16x16x32_bf16(Af[2][ks], bfr, a2, 0, 0, 0);
        }

        // h[b][n0..n0+3] = tanh(acc + xp); pad cols: acc=0, xc=0 -> tanh(0)=0
        {
            int n0 = w * 16 + q * 4;
            u32x2 pk;
            pk[0] = pack2(tanh_fast(a0[0] + bf2f((u16)xc[0][0])),
                          tanh_fast(a0[1] + bf2f((u16)xc[0][1])));
            pk[1] = pack2(tanh_fast(a0[2] + bf2f((u16)xc[0][2])),
                          tanh_fast(a0[3] + bf2f((u16)xc[0][3])));
            *(u32x2*)&hn[br * 328 + n0] = pk;
        }
        {
            int n0 = (w + 8) * 16 + q * 4;
            u32x2 pk;
            pk[0] = pack2(tanh_fast(a1[0] + bf2f((u16)xc[1][0])),
                          tanh_fast(a1[1] + bf2f((u16)xc[1][1])));
            pk[1] = pack2(tanh_fast(a1[2] + bf2f((u16)xc[1][2])),
                          tanh_fast(a1[3] + bf2f((u16)xc[1][3])));
            *(u32x2*)&hn[br * 328 + n0] = pk;
        }
        if (t3) {
            int n0 = (w + 16) * 16 + q * 4;
            u32x2 pk;
            pk[0] = pack2(tanh_fast(a2[0] + bf2f((u16)xc[2][0])),
                          tanh_fast(a2[1] + bf2f((u16)xc[2][1])));
            pk[1] = pack2(tanh_fast(a2[2] + bf2f((u16)xc[2][2])),
                          tanh_fast(a2[3] + bf2f((u16)xc[2][3])));
            *(u32x2*)&hn[br * 328 + n0] = pk;
        }
        lds_barrier();   // LDS-only ordering; xp loads stay in flight

#pragma unroll
        for (int j = 0; j < 3; ++j) { xc[j] = xn[j]; xn[j] = xf[j]; }
    }

    // epilogue: t1&1 == 0 for both splits (256, 512) -> h lives in hb[0]
    const u16* hf = hb[0];
    if (t1 == SEQ) {
        for (int i = tid; i < 16 * HID; i += 512) {
            int r = i / HID, n = i - r * HID;
            out[(size_t)(b0 + r) * HID + n] = bf2f(hf[r * 328 + n]);
        }
    } else {
        u16* hs = (u16*)out;
        for (int i = tid; i < 16 * HID; i += 512) {
            int r = i / HID, n = i - r * HID;
            hs[(size_t)(b0 + r) * HID + n] = hf[r * 328 + n];
        }
    }
}

// ---------------------------------------------------------------------------
extern "C" void kernel_launch(void* const* d_in, const int* in_sizes, int n_in,
                              void* d_out, int out_size, void* d_ws, size_t ws_size,
                              hipStream_t stream) {
    const float* in  = (const float*)d_in[0];
    const float* wih = (const float*)d_in[1];
    const float* whh = (const float*)d_in[2];
    const float* bih = (const float*)d_in[3];
    const float* bhh = (const float*)d_in[4];

    char* ws = (char*)d_ws;
    const size_t XP_BYTES = (size_t)MTOT * HID * sizeof(u16);   // 157,286,400
    u16*   xpb  = (u16*)ws;
    u16*   wihp = (u16*)(ws + XP_BYTES);
    u16*   whhp = (u16*)(ws + XP_BYTES + (size_t)KP * KP * 2);
    float* bias = (float*)(ws + XP_BYTES + 2 * (size_t)KP * KP * 2);

    prep_kernel<<<KP, KP, 0, stream>>>(wih, whh, bih, bhh, wihp, whhp, bias);
    xproj_kernel<<<MTOT / 128, 512, 0, stream>>>(in, wihp, bias, xpb);
    rnn_recur_kernel<<<BZ / 16, 512, 0, stream>>>(xpb, whhp, (float*)d_out, 0, SEQ / 2);
    rnn_recur_kernel<<<BZ / 16, 512, 0, stream>>>(xpb, whhp, (float*)d_out, SEQ / 2, SEQ);
}